// Round 9
// baseline (593.546 us; speedup 1.0000x reference)
//
#include <hip/hip_runtime.h>

// WaveInputEncoder on MI355X — round 9.
// vs r8: GEMMs reverted off 32x32 (conflict regression) and rebuilt as the
// m97-style 128^2 high-TLP kernel: 256 thr / 4 waves, BK=64 single-buffered
// 32KB LDS, plain __syncthreads, 4 blocks/CU (implicit wave-level overlap),
// r7's verified 0-conflict swizzle, global_load_lds(16B) staging.
// If ws_size allows (~196MB), GEMMs run full-M in one dispatch each.

typedef __attribute__((ext_vector_type(8))) short s16x8;
typedef __attribute__((ext_vector_type(4))) short s16x4;
typedef __attribute__((ext_vector_type(4))) float f32x4;

__device__ __forceinline__ short f2bf(float x){
  unsigned u = __float_as_uint(x);
  unsigned r = (u + 0x7fffu + ((u >> 16) & 1u)) >> 16;   // RNE
  return (short)r;
}
__device__ __forceinline__ float bf2f(short x){
  return __uint_as_float(((unsigned)(unsigned short)x) << 16);
}
__device__ __forceinline__ void gload16(const void* g, void* l){
  __builtin_amdgcn_global_load_lds((const __attribute__((address_space(1))) void*)g,
                                   (__attribute__((address_space(3))) void*)l, 16, 0, 0);
}
__device__ __forceinline__ float gelu_f(float v){
  float u2 = v * (0.7978845608f + 0.0356774081f * v * v);
  float e = __expf(2.0f * u2);
  float th = 1.0f - 2.0f / (e + 1.0f);
  return 0.5f * v * (1.0f + th);
}

// ---------------- prep kernels ----------------
__global__ void prep_wcs_k(const float* __restrict__ mw, const float* __restrict__ po,
                           float* __restrict__ wcs){
  int i = threadIdx.x;
  if (i < 32){
    wcs[i]      = log1pf(expf(mw[i]));  // softplus
    wcs[32 + i] = cosf(po[i]);
    wcs[64 + i] = sinf(po[i]);
  }
}

__global__ __launch_bounds__(256) void prep_tab_k(float* __restrict__ ctab, float* __restrict__ stab){
  int idx = blockIdx.x * 256 + threadIdx.x;      // idx = m*4096 + t
  int m = idx >> 12, t = idx & 4095;
  int r = (m * t) & 4095;
  float ang = (float)r * 1.5339807878856412e-3f; // 2*pi/4096
  float s, c; sincosf(ang, &s, &c);
  ctab[idx] = c; stab[idx] = s;
}

// transpose fp32 (R x C) -> bf16 (C x R), 64x64 LDS tiles
__global__ __launch_bounds__(256) void transpose_bf16_k(const float* __restrict__ src,
                                                        short* __restrict__ dst,
                                                        int R, int C){
  __shared__ float tile[64][65];
  int c0 = blockIdx.x * 64, r0 = blockIdx.y * 64;
  for (int i = 0; i < 16; ++i){
    int idx = i * 256 + threadIdx.x;
    int rr = idx >> 6, cc = idx & 63;
    tile[rr][cc] = src[(size_t)(r0 + rr) * C + c0 + cc];
  }
  __syncthreads();
  for (int i = 0; i < 16; ++i){
    int idx = i * 256 + threadIdx.x;
    int cc = idx >> 6, rr = idx & 63;
    dst[(size_t)(c0 + cc) * R + r0 + rr] = f2bf(tile[rr][cc]);
  }
}

// ---------------- kernel A ----------------
__global__ __launch_bounds__(256) void kernelA(const int* __restrict__ tokens,
    const float* __restrict__ frw, const float* __restrict__ fiw,
    const float* __restrict__ wcs, const float* __restrict__ ftew,
    const float* __restrict__ fteb, const float* __restrict__ posph,
    float* __restrict__ xout){
  __shared__ float ffs[4][64];
  __shared__ float xs[4][1024];
  __shared__ float wsh[96];
  int tid = threadIdx.x;
  int b = blockIdx.x >> 10, t0 = (blockIdx.x & 1023) * 4;
  if (tid < 96) wsh[tid] = wcs[tid];
  __syncthreads();
  if (tid < 128){
    int tk = tid >> 5, m = tid & 31;
    int tok = tokens[b * 4096 + t0 + tk];
    float w = wsh[m];
    float re = frw[(size_t)tok * 32 + m] * w;
    float im = fiw[(size_t)tok * 32 + m] * w;
    float c = wsh[32 + m], s = wsh[64 + m];
    ffs[tk][m]      = re * c - im * s;
    ffs[tk][32 + m] = re * s + im * c;
  }
  __syncthreads();
  for (int p = 0; p < 4; ++p){
    int dd = p * 256 + tid;
    float bb = fteb[dd];
    float a0 = bb, a1 = bb, a2 = bb, a3 = bb;
    #pragma unroll 8
    for (int k = 0; k < 64; ++k){
      float wv = ftew[k * 1024 + dd];
      a0 += ffs[0][k] * wv; a1 += ffs[1][k] * wv;
      a2 += ffs[2][k] * wv; a3 += ffs[3][k] * wv;
    }
    xs[0][dd] = a0; xs[1][dd] = a1; xs[2][dd] = a2; xs[3][dd] = a3;
  }
  __syncthreads();
  for (int p = 0; p < 4; ++p){
    int dd = p * 256 + tid, dm = (dd + 1023) & 1023;
    #pragma unroll
    for (int tk = 0; tk < 4; ++tk){
      float pp = posph[(size_t)(t0 + tk) * 1024 + dd];
      float p2 = pp * pp;
      float sp = pp * (1.0f - p2 * (1.0f/6.0f) + p2 * p2 * (1.0f/120.0f));
      float cp = 1.0f - p2 * 0.5f + p2 * p2 * (1.0f/24.0f);
      xout[((size_t)b * 4096 + t0 + tk) * 1024 + dd] = xs[tk][dd] * cp + xs[tk][dm] * sp;
    }
  }
}

// ---------------- kernel B: truncated forward DFT via rotation recurrence ----------------
__global__ __launch_bounds__(256) void kernelB2(const float* __restrict__ xin,
    float* __restrict__ Pr, float* __restrict__ Pi){
  __shared__ float xsh[64][32];
  int tid = threadIdx.x;
  int bx = blockIdx.x;
  int b = bx >> 8, dch = (bx >> 3) & 31, tc = bx & 7;
  int d0 = dch * 32;
  int t_start = tc * 512;
  int dg = tid >> 5, m = tid & 31;
  const float TPN = 1.5339807878856412e-3f;
  int r0 = (m * t_start) & 4095;
  float cw, sw; sincosf(-(float)r0 * TPN, &sw, &cw);
  float cs, ss; sincosf(-(float)m * TPN, &ss, &cs);
  float ar[4] = {0,0,0,0}, ai[4] = {0,0,0,0};
  for (int t0 = t_start; t0 < t_start + 512; t0 += 64){
    __syncthreads();
    #pragma unroll
    for (int i = 0; i < 2; ++i){
      int unit = i * 256 + tid;
      int tt = unit >> 3, du = (unit & 7) * 4;
      *(f32x4*)&xsh[tt][du] = *(const f32x4*)&xin[((size_t)b * 4096 + t0 + tt) * 1024 + d0 + du];
    }
    __syncthreads();
    #pragma unroll 4
    for (int tt = 0; tt < 64; ++tt){
      f32x4 xv = *(const f32x4*)&xsh[tt][dg * 4];
      #pragma unroll
      for (int j = 0; j < 4; ++j){ ar[j] += xv[j] * cw; ai[j] += xv[j] * sw; }
      float cn = cw * cs - sw * ss;
      sw = cw * ss + sw * cs; cw = cn;
    }
  }
  #pragma unroll
  for (int j = 0; j < 4; ++j){
    int d = d0 + dg * 4 + j;
    size_t idx = (((size_t)tc * 4 + b) * 1024 + d) * 32 + m;
    Pr[idx] = ar[j]; Pi[idx] = ai[j];
  }
}

__global__ __launch_bounds__(256) void reduceB_k(const float* __restrict__ Pr,
    const float* __restrict__ Pi, float* __restrict__ Xr, float* __restrict__ Xi){
  int lin = blockIdx.x * 256 + threadIdx.x;
  int m = lin & 31, d = (lin >> 5) & 1023, b = lin >> 15;
  float sr = 0.0f, si = 0.0f;
  for (int tc = 0; tc < 8; ++tc){
    size_t idx = (((size_t)tc * 4 + b) * 1024 + d) * 32 + m;
    sr += Pr[idx]; si += Pi[idx];
  }
  int n = d >> 7, jj = d & 127;
  size_t o = (((size_t)b * 8 + n) * 32 + m) * 128 + jj;
  Xr[o] = sr * 0.015625f; Xi[o] = si * 0.015625f;
}

// ---------------- kernel C ----------------
__global__ __launch_bounds__(128) void kernelC(const float* __restrict__ Xr, const float* __restrict__ Xi,
    const float* __restrict__ awr, const float* __restrict__ awi,
    float* __restrict__ Or, float* __restrict__ Oi){
  __shared__ float xr_s[4][128], xi_s[4][128];
  int nm = blockIdx.x; int n = nm >> 5, m = nm & 31;
  int i = threadIdx.x;
  for (int b = 0; b < 4; ++b){
    size_t src = (((size_t)b * 8 + n) * 32 + m) * 128 + i;
    xr_s[b][i] = Xr[src]; xi_s[b][i] = Xi[src];
  }
  __syncthreads();
  float accr[4] = {0,0,0,0}, acci[4] = {0,0,0,0};
  size_t wb = (((size_t)n * 32 + m) * 128 + i) * 128;
  for (int j = 0; j < 128; ++j){
    float wr = awr[wb + j], wi = awi[wb + j];
    #pragma unroll
    for (int b = 0; b < 4; ++b){
      accr[b] += wr * xr_s[b][j] - wi * xi_s[b][j];
      acci[b] += wr * xi_s[b][j] + wi * xr_s[b][j];
    }
  }
  #pragma unroll
  for (int b = 0; b < 4; ++b){
    float vr = accr[b], vi = acci[b];
    vr = vr > 0.01f ? vr - 0.01f : (vr < -0.01f ? vr + 0.01f : 0.0f);
    vi = vi > 0.01f ? vi - 0.01f : (vi < -0.01f ? vi + 0.01f : 0.0f);
    size_t dst = ((size_t)b * 32 + m) * 1024 + n * 128 + i;  // [b][m][d]
    Or[dst] = vr; Oi[dst] = vi;
  }
}

// ---------------- kernel D3: d-chunked irfft + residual in-place ----------------
__global__ __launch_bounds__(256) void kernelD3(const float* __restrict__ Or, const float* __restrict__ Oi,
    const float* __restrict__ ctab, const float* __restrict__ stab, float* __restrict__ y){
  __shared__ float cts[32][64], sts[32][64];
  __shared__ float Ors[32][144], Ois[32][144];
  int tid = threadIdx.x;
  int bx = blockIdx.x;
  int b = bx >> 9, tc = (bx >> 3) & 63, dc = bx & 7;
  int t0 = tc * 64, d0 = dc * 128;
  for (int i = 0; i < 8; ++i){
    int lin = i * 256 + tid;
    int m = lin >> 6, tl = lin & 63;
    float f = (m == 0 ? 1.0f : 2.0f) * 0.015625f;
    cts[m][tl] = ctab[m * 4096 + t0 + tl] * f;
    sts[m][tl] = stab[m * 4096 + t0 + tl] * f;
  }
  for (int i = 0; i < 4; ++i){
    int lin = i * 256 + tid;
    int m = lin >> 5, q = lin & 31;
    int w = q * 4;
    int ph = w + ((w >> 5) << 2);
    size_t src = ((size_t)b * 32 + m) * 1024 + d0 + w;
    *(f32x4*)&Ors[m][ph] = *(const f32x4*)&Or[src];
    *(f32x4*)&Ois[m][ph] = *(const f32x4*)&Oi[src];
  }
  __syncthreads();
  int tt = tid >> 4, dl = tid & 15;
  int wb0 = dl * 8;
  int ph0 = wb0 + ((wb0 >> 5) << 2);
  int ph1 = ph0 + 4;
  float acc[4][8];
  #pragma unroll
  for (int q = 0; q < 4; ++q)
    #pragma unroll
    for (int j = 0; j < 8; ++j) acc[q][j] = 0.f;
  for (int m = 0; m < 32; ++m){
    f32x4 cv = *(const f32x4*)&cts[m][tt * 4];
    f32x4 sv = *(const f32x4*)&sts[m][tt * 4];
    f32x4 orv0 = *(const f32x4*)&Ors[m][ph0];
    f32x4 orv1 = *(const f32x4*)&Ors[m][ph1];
    f32x4 oiv0 = *(const f32x4*)&Ois[m][ph0];
    f32x4 oiv1 = *(const f32x4*)&Ois[m][ph1];
    #pragma unroll
    for (int q = 0; q < 4; ++q){
      #pragma unroll
      for (int e = 0; e < 4; ++e){
        acc[q][e]     += cv[q] * orv0[e] - sv[q] * oiv0[e];
        acc[q][4 + e] += cv[q] * orv1[e] - sv[q] * oiv1[e];
      }
    }
  }
  #pragma unroll
  for (int q = 0; q < 4; ++q){
    size_t row = ((size_t)b * 4096 + t0 + tt * 4 + q) * 1024 + d0 + dl * 8;
    f32x4 r0 = *(const f32x4*)&y[row];
    f32x4 r1 = *(const f32x4*)&y[row + 4];
    #pragma unroll
    for (int e = 0; e < 4; ++e){ r0[e] += acc[q][e]; r1[e] += acc[q][4 + e]; }
    *(f32x4*)&y[row] = r0;
    *(f32x4*)&y[row + 4] = r1;
  }
}

// ---------------- LN1: y (f32) -> xln1 (bf16) ----------------
__global__ __launch_bounds__(256) void ln1_k(const float* __restrict__ y,
    const float* __restrict__ g, const float* __restrict__ bb, short* __restrict__ xln){
  size_t row = blockIdx.x;
  int tid = threadIdx.x;
  f32x4 v = *(const f32x4*)(y + row * 1024 + tid * 4);
  float sum = v[0] + v[1] + v[2] + v[3];
  float sq  = v[0]*v[0] + v[1]*v[1] + v[2]*v[2] + v[3]*v[3];
  for (int off = 32; off; off >>= 1){ sum += __shfl_down(sum, off); sq += __shfl_down(sq, off); }
  __shared__ float rs[4], rq[4];
  int lane = tid & 63, w = tid >> 6;
  if (lane == 0){ rs[w] = sum; rq[w] = sq; }
  __syncthreads();
  sum = rs[0] + rs[1] + rs[2] + rs[3]; sq = rq[0] + rq[1] + rq[2] + rq[3];
  float mu = sum * (1.0f / 1024.0f);
  float var = sq * (1.0f / 1024.0f) - mu * mu;
  float sc = rsqrtf(var + 1e-5f);
  s16x4 o;
  #pragma unroll
  for (int j = 0; j < 4; ++j){
    int d = tid * 4 + j;
    o[j] = f2bf((v[j] - mu) * sc * g[d] + bb[d]);
  }
  *(s16x4*)(xln + row * 1024 + tid * 4) = o;
}

// ---------------- m97-style 128^2 high-TLP bf16 MFMA GEMM ----------------
// 256 thr / 4 waves (2x2), wave = 64x64 (4x4 frags of 16x16x32), BK=64,
// single-buffered 32KB LDS, 4 blocks/CU. Swizzle: stage source pre-swizzled
// (slot = (k8grp ^ (row&7))), read at slot ((ks*4+lg) ^ (lr&7)) — 0-conflict
// pattern verified in r7. EPI 0: gelu->bf16 Hout (stride N). EPI 1:
// +bias+resid -> f32 Fout (stride 1024, rows offset by row0_abs).
template<int EPI>
__global__ __launch_bounds__(256, 4) void gemm128_k(const short* __restrict__ A,
    const short* __restrict__ BT, const float* __restrict__ bias,
    const short* __restrict__ resid, short* __restrict__ Hout,
    float* __restrict__ Fout, int K, int N, int nMB, long row0_abs){
  __shared__ __align__(16) short As[8192];
  __shared__ __align__(16) short Bs[8192];
  const int tid = threadIdx.x;
  const int lane = tid & 63, wv = tid >> 6;
  const int wr = wv >> 1, wc = wv & 1;
  const int lr = lane & 15, lg = lane >> 4;

  // XCD-contiguous block mapping (grid % 8 == 0 for all grids used)
  const int nwg = gridDim.x;
  const int xcd = blockIdx.x & 7, lidx = blockIdx.x >> 3;
  const int swz = xcd * (nwg >> 3) + lidx;
  const int mb = swz % nMB, nb = swz / nMB;
  const long arow0 = (long)mb * 128;
  const long bcol0 = (long)nb * 128;
  const int NT = K >> 6;

  // staging addresses: per-lane source (pre-swizzled), wave-uniform LDS dest
  const int rr = tid >> 3;                           // 0..31 (8 rows/wave)
  const int sl8 = ((tid & 7) ^ (rr & 7)) * 8;        // inverse-swizzled k-slot
  const long aoff = (long)rr * K + sl8;
  const short* Au = A  + arow0 * K;
  const short* Bu = BT + bcol0 * K;
  const int ldsw = wv * 512;                         // shorts (wave slot)

  // fragment read bases (row = wr*64 + mi*16 + lr; R&7 == lr&7)
  const int aR = (wr * 64 + lr) * 64;
  const int bR = (wc * 64 + lr) * 64;
  const int asl0 = ((lg)     ^ (lr & 7)) * 8;        // ks=0 slot
  const int asl1 = ((4 + lg) ^ (lr & 7)) * 8;        // ks=1 slot

  f32x4 acc[4][4] = {};

  for (int t = 0; t < NT; ++t){
    const long kof = (long)t * 64;
    #pragma unroll
    for (int u = 0; u < 4; ++u)
      gload16(Au + (long)(u * 32) * K + kof + aoff, As + u * 2048 + ldsw);
    #pragma unroll
    for (int u = 0; u < 4; ++u)
      gload16(Bu + (long)(u * 32) * K + kof + aoff, Bs + u * 2048 + ldsw);
    __syncthreads();
    #pragma unroll
    for (int ks = 0; ks < 2; ++ks){
      const int so = ks ? asl1 : asl0;
      s16x8 af[4], bf[4];
      #pragma unroll
      for (int mi = 0; mi < 4; ++mi) af[mi] = *(const s16x8*)&As[aR + mi * 1024 + so];
      #pragma unroll
      for (int ni = 0; ni < 4; ++ni) bf[ni] = *(const s16x8*)&Bs[bR + ni * 1024 + so];
      #pragma unroll
      for (int mi = 0; mi < 4; ++mi)
        #pragma unroll
        for (int ni = 0; ni < 4; ++ni)
          acc[mi][ni] = __builtin_amdgcn_mfma_f32_16x16x32_bf16(af[mi], bf[ni], acc[mi][ni], 0, 0, 0);
    }
    __syncthreads();
  }

  // epilogue: C/D col = lane&15, row = (lane>>4)*4 + reg
  const int rb = lg * 4;
  #pragma unroll
  for (int mi = 0; mi < 4; ++mi){
    #pragma unroll
    for (int ni = 0; ni < 4; ++ni){
      int cl = (int)bcol0 + wc * 64 + ni * 16 + lr;
      float bv = bias[cl];
      #pragma unroll
      for (int i = 0; i < 4; ++i){
        long rl = arow0 + wr * 64 + mi * 16 + rb + i;
        float v = acc[mi][ni][i] + bv;
        if constexpr (EPI == 0){
          Hout[rl * (long)N + cl] = f2bf(gelu_f(v));
        } else {
          float rv = bf2f(resid[(row0_abs + rl) * 1024 + cl]);
          Fout[(row0_abs + rl) * 1024 + cl] = v + rv;
        }
      }
    }
  }
}

// ---------------- LN2 in-place on f32 out ----------------
__global__ __launch_bounds__(256) void ln2_k(float* __restrict__ out,
    const float* __restrict__ g, const float* __restrict__ bb){
  size_t row = blockIdx.x;
  int tid = threadIdx.x;
  float* p = out + row * 1024;
  f32x4 v = *(const f32x4*)(p + tid * 4);
  float sum = v[0] + v[1] + v[2] + v[3];
  float sq  = v[0]*v[0] + v[1]*v[1] + v[2]*v[2] + v[3]*v[3];
  for (int off = 32; off; off >>= 1){ sum += __shfl_down(sum, off); sq += __shfl_down(sq, off); }
  __shared__ float rs[4], rq[4];
  int lane = tid & 63, w = tid >> 6;
  if (lane == 0){ rs[w] = sum; rq[w] = sq; }
  __syncthreads();
  sum = rs[0] + rs[1] + rs[2] + rs[3]; sq = rq[0] + rq[1] + rq[2] + rq[3];
  float mu = sum * (1.0f / 1024.0f);
  float var = sq * (1.0f / 1024.0f) - mu * mu;
  float sc = rsqrtf(var + 1e-5f);
  f32x4 o;
  #pragma unroll
  for (int j = 0; j < 4; ++j){
    int d = tid * 4 + j;
    o[j] = (v[j] - mu) * sc * g[d] + bb[d];
  }
  *(f32x4*)(p + tid * 4) = o;
}

// ---------------- launch ----------------
extern "C" void kernel_launch(void* const* d_in, const int* in_sizes, int n_in,
                              void* d_out, int out_size, void* d_ws, size_t ws_size,
                              hipStream_t stream){
  (void)in_sizes; (void)n_in; (void)out_size;
  const int*   tokens = (const int*)d_in[0];
  const float* frw  = (const float*)d_in[1];
  const float* fiw  = (const float*)d_in[2];
  const float* mw   = (const float*)d_in[3];
  const float* po   = (const float*)d_in[4];
  const float* ftew = (const float*)d_in[5];
  const float* fteb = (const float*)d_in[6];
  const float* posph= (const float*)d_in[7];
  const float* awr  = (const float*)d_in[8];
  const float* awi  = (const float*)d_in[9];
  const float* ln1g = (const float*)d_in[10];
  const float* ln1b = (const float*)d_in[11];
  const float* w1   = (const float*)d_in[12];
  const float* b1   = (const float*)d_in[13];
  const float* w2   = (const float*)d_in[14];
  const float* b2   = (const float*)d_in[15];
  const float* ln2g = (const float*)d_in[16];
  const float* ln2b = (const float*)d_in[17];
  float* out = (float*)d_out;

  // big path: full-M hbuf (16384x4096 bf16 = 134.2MB), residual aliases its head.
  const size_t HB_BIG   = (size_t)16384 * 4096 * 2;
  const size_t HB_SMALL = (size_t)8192 * 4096 * 2;   // == residual 67.1MB
  const size_t TAIL     = (size_t)16384 * 1024 * 2   // xln1
                        + 2 * (size_t)4096 * 1024 * 2 // w1b, w2b
                        + 6 * 524288                  // ctab..Oi
                        + 2 * (size_t)4194304         // Pr, Pi
                        + 512;                        // wcs
  const bool big = ws_size >= HB_BIG + TAIL;
  const size_t hb = big ? HB_BIG : HB_SMALL;

  char* ws = (char*)d_ws;
  size_t o = 0;
  float* residual = (float*)(ws + o); o += hb;                          // head doubles as hbuf
  short* hbuf     = (short*)residual;
  short* xln1     = (short*)(ws + o); o += (size_t)16384 * 1024 * 2;
  short* w1b      = (short*)(ws + o); o += (size_t)4096 * 1024 * 2;
  short* w2b      = (short*)(ws + o); o += (size_t)4096 * 1024 * 2;
  float* ctab     = (float*)(ws + o); o += 524288;
  float* stab     = (float*)(ws + o); o += 524288;
  float* Xr       = (float*)(ws + o); o += 524288;
  float* Xi       = (float*)(ws + o); o += 524288;
  float* Or       = (float*)(ws + o); o += 524288;
  float* Oi       = (float*)(ws + o); o += 524288;
  float* Pr       = (float*)(ws + o); o += 4194304;
  float* Pi       = (float*)(ws + o); o += 4194304;
  float* wcs      = (float*)(ws + o); o += 512;

  prep_wcs_k<<<1, 64, 0, stream>>>(mw, po, wcs);
  prep_tab_k<<<512, 256, 0, stream>>>(ctab, stab);
  transpose_bf16_k<<<dim3(64, 16), 256, 0, stream>>>(w1, w1b, 1024, 4096);
  transpose_bf16_k<<<dim3(16, 64), 256, 0, stream>>>(w2, w2b, 4096, 1024);

  kernelA<<<4096, 256, 0, stream>>>(tokens, frw, fiw, wcs, ftew, fteb, posph, residual);
  kernelB2<<<1024, 256, 0, stream>>>(residual, Pr, Pi);
  reduceB_k<<<512, 256, 0, stream>>>(Pr, Pi, Xr, Xi);
  kernelC<<<256, 128, 0, stream>>>(Xr, Xi, awr, awi, Or, Oi);
  kernelD3<<<2048, 256, 0, stream>>>(Or, Oi, ctab, stab, residual);
  ln1_k<<<16384, 256, 0, stream>>>(residual, ln1g, ln1b, xln1);

  if (big){
    // full-M: gemm1 grid 128x32=4096 blocks (4/CU), gemm2 grid 128x8=1024 (4/CU)
    gemm128_k<0><<<4096, 256, 0, stream>>>(xln1, w1b, b1, nullptr, hbuf, nullptr,
                                           1024, 4096, 128, 0);
    gemm128_k<1><<<1024, 256, 0, stream>>>(hbuf, w2b, b2, xln1, nullptr, out,
                                           4096, 1024, 128, 0);
  } else {
    for (int c = 0; c < 2; ++c){
      long row0 = (long)c * 8192;
      gemm128_k<0><<<2048, 256, 0, stream>>>(xln1 + row0 * 1024, w1b, b1, nullptr,
                                             hbuf, nullptr, 1024, 4096, 64, 0);
      gemm128_k<1><<<512, 256, 0, stream>>>(hbuf, w2b, b2, xln1, nullptr, out,
                                            4096, 1024, 64, row0);
    }
  }
  ln2_k<<<16384, 256, 0, stream>>>(out, ln2g, ln2b);
}

// Round 10
// 563.508 us; speedup vs baseline: 1.0533x; 1.0533x over previous
//
#include <hip/hip_runtime.h>

// WaveInputEncoder on MI355X — round 10.
// vs r9: GEMMs reverted to r7 (best measured: 256^2 4-phase, 87.5us, 0-conflict).
// kernelA restructured: block = 4 t-positions x all 4 batches (posph/trig shared,
// ftew L2 traffic /4, 16 accums ILP). prep_wcs fused into prep_tab; reduceB fused
// into kernelC. 11 dispatches total.

typedef __attribute__((ext_vector_type(8))) short s16x8;
typedef __attribute__((ext_vector_type(4))) short s16x4;
typedef __attribute__((ext_vector_type(4))) float f32x4;

#define SCHED0 __builtin_amdgcn_sched_barrier(0)
#define BARR   __builtin_amdgcn_s_barrier()
#define LGKM0  asm volatile("s_waitcnt lgkmcnt(0)" ::: "memory")
#define VM(n)  asm volatile("s_waitcnt vmcnt(" #n ")" ::: "memory")

__device__ __forceinline__ short f2bf(float x){
  unsigned u = __float_as_uint(x);
  unsigned r = (u + 0x7fffu + ((u >> 16) & 1u)) >> 16;   // RNE
  return (short)r;
}
__device__ __forceinline__ float bf2f(short x){
  return __uint_as_float(((unsigned)(unsigned short)x) << 16);
}
__device__ __forceinline__ void gload16(const void* g, void* l){
  __builtin_amdgcn_global_load_lds((const __attribute__((address_space(1))) void*)g,
                                   (__attribute__((address_space(3))) void*)l, 16, 0, 0);
}
__device__ __forceinline__ float gelu_f(float v){
  float u2 = v * (0.7978845608f + 0.0356774081f * v * v);
  float e = __expf(2.0f * u2);
  float th = 1.0f - 2.0f / (e + 1.0f);
  return 0.5f * v * (1.0f + th);
}

// ---------------- prep: DFT tables + (block 511) softplus/rot consts ----------------
__global__ __launch_bounds__(256) void prep_tab_k(float* __restrict__ ctab, float* __restrict__ stab,
    const float* __restrict__ mw, const float* __restrict__ po, float* __restrict__ wcs){
  int idx = blockIdx.x * 256 + threadIdx.x;      // idx = m*4096 + t
  int m = idx >> 12, t = idx & 4095;
  int r = (m * t) & 4095;
  float ang = (float)r * 1.5339807878856412e-3f; // 2*pi/4096
  float s, c; sincosf(ang, &s, &c);
  ctab[idx] = c; stab[idx] = s;
  if (blockIdx.x == 511 && threadIdx.x < 32){
    int i = threadIdx.x;
    wcs[i]      = log1pf(expf(mw[i]));
    wcs[32 + i] = cosf(po[i]);
    wcs[64 + i] = sinf(po[i]);
  }
}

// transpose fp32 (R x C) -> bf16 (C x R), 64x64 LDS tiles
__global__ __launch_bounds__(256) void transpose_bf16_k(const float* __restrict__ src,
                                                        short* __restrict__ dst,
                                                        int R, int C){
  __shared__ float tile[64][65];
  int c0 = blockIdx.x * 64, r0 = blockIdx.y * 64;
  for (int i = 0; i < 16; ++i){
    int idx = i * 256 + threadIdx.x;
    int rr = idx >> 6, cc = idx & 63;
    tile[rr][cc] = src[(size_t)(r0 + rr) * C + c0 + cc];
  }
  __syncthreads();
  for (int i = 0; i < 16; ++i){
    int idx = i * 256 + threadIdx.x;
    int cc = idx >> 6, rr = idx & 63;
    dst[(size_t)(c0 + cc) * R + r0 + rr] = f2bf(tile[rr][cc]);
  }
}

// ---------------- kernel A: embed + rotate + FTE + positional phase ----------------
// grid 1024 (t-chunks of 4); block = 4 t x 4 batches (posph/trig shared)
__global__ __launch_bounds__(256) void kernelA2(const int* __restrict__ tokens,
    const float* __restrict__ frw, const float* __restrict__ fiw,
    const float* __restrict__ wcs, const float* __restrict__ ftew,
    const float* __restrict__ fteb, const float* __restrict__ posph,
    float* __restrict__ xout){
  __shared__ float ffs[16][64];
  __shared__ float xs[16][1024];   // 64 KB
  __shared__ float wsh[96];
  int tid = threadIdx.x;
  int t0 = blockIdx.x * 4;
  if (tid < 96) wsh[tid] = wcs[tid];
  __syncthreads();
  #pragma unroll
  for (int i = 0; i < 2; ++i){
    int idx = i * 256 + tid;            // 512 = 16 tk x 32 m
    int tk = idx >> 5, m = idx & 31;
    int b = tk >> 2, dt = tk & 3;
    int tok = tokens[b * 4096 + t0 + dt];
    float w = wsh[m];
    float re = frw[(size_t)tok * 32 + m] * w;
    float im = fiw[(size_t)tok * 32 + m] * w;
    float c = wsh[32 + m], s = wsh[64 + m];
    ffs[tk][m]      = re * c - im * s;
    ffs[tk][32 + m] = re * s + im * c;
  }
  __syncthreads();
  for (int p = 0; p < 4; ++p){
    int dd = p * 256 + tid;
    float bb = fteb[dd];
    float a[16];
    #pragma unroll
    for (int j = 0; j < 16; ++j) a[j] = bb;
    #pragma unroll 4
    for (int k = 0; k < 64; ++k){
      float wv = ftew[k * 1024 + dd];
      #pragma unroll
      for (int j = 0; j < 16; ++j) a[j] += ffs[j][k] * wv;
    }
    #pragma unroll
    for (int j = 0; j < 16; ++j) xs[j][dd] = a[j];
  }
  __syncthreads();
  for (int p = 0; p < 4; ++p){
    int dd = p * 256 + tid, dm = (dd + 1023) & 1023;  // roll(+1): x[d-1 mod D]
    #pragma unroll
    for (int dt = 0; dt < 4; ++dt){
      float pp = posph[(size_t)(t0 + dt) * 1024 + dd];
      float p2 = pp * pp;
      float sp = pp * (1.0f - p2 * (1.0f/6.0f) + p2 * p2 * (1.0f/120.0f));
      float cp = 1.0f - p2 * 0.5f + p2 * p2 * (1.0f/24.0f);
      #pragma unroll
      for (int b = 0; b < 4; ++b){
        int tk = b * 4 + dt;
        xout[((size_t)b * 4096 + t0 + dt) * 1024 + dd] = xs[tk][dd] * cp + xs[tk][dm] * sp;
      }
    }
  }
}

// ---------------- kernel B: truncated forward DFT via rotation recurrence ----------------
__global__ __launch_bounds__(256) void kernelB2(const float* __restrict__ xin,
    float* __restrict__ Pr, float* __restrict__ Pi){
  __shared__ float xsh[64][32];
  int tid = threadIdx.x;
  int bx = blockIdx.x;
  int b = bx >> 8, dch = (bx >> 3) & 31, tc = bx & 7;
  int d0 = dch * 32;
  int t_start = tc * 512;
  int dg = tid >> 5, m = tid & 31;
  const float TPN = 1.5339807878856412e-3f;
  int r0 = (m * t_start) & 4095;
  float cw, sw; sincosf(-(float)r0 * TPN, &sw, &cw);
  float cs, ss; sincosf(-(float)m * TPN, &ss, &cs);
  float ar[4] = {0,0,0,0}, ai[4] = {0,0,0,0};
  for (int t0 = t_start; t0 < t_start + 512; t0 += 64){
    __syncthreads();
    #pragma unroll
    for (int i = 0; i < 2; ++i){
      int unit = i * 256 + tid;
      int tt = unit >> 3, du = (unit & 7) * 4;
      *(f32x4*)&xsh[tt][du] = *(const f32x4*)&xin[((size_t)b * 4096 + t0 + tt) * 1024 + d0 + du];
    }
    __syncthreads();
    #pragma unroll 4
    for (int tt = 0; tt < 64; ++tt){
      f32x4 xv = *(const f32x4*)&xsh[tt][dg * 4];
      #pragma unroll
      for (int j = 0; j < 4; ++j){ ar[j] += xv[j] * cw; ai[j] += xv[j] * sw; }
      float cn = cw * cs - sw * ss;
      sw = cw * ss + sw * cs; cw = cn;
    }
  }
  #pragma unroll
  for (int j = 0; j < 4; ++j){
    int d = d0 + dg * 4 + j;
    size_t idx = (((size_t)tc * 4 + b) * 1024 + d) * 32 + m;
    Pr[idx] = ar[j]; Pi[idx] = ai[j];
  }
}

// ---------------- kernel C (with fused tc-reduction of Pr/Pi) ----------------
__global__ __launch_bounds__(128) void kernelC2(const float* __restrict__ Pr, const float* __restrict__ Pi,
    const float* __restrict__ awr, const float* __restrict__ awi,
    float* __restrict__ Or, float* __restrict__ Oi){
  __shared__ float xr_s[4][128], xi_s[4][128];
  int nm = blockIdx.x; int n = nm >> 5, m = nm & 31;
  int i = threadIdx.x;
  #pragma unroll
  for (int b = 0; b < 4; ++b){
    float sr = 0.0f, si = 0.0f;
    #pragma unroll
    for (int tc = 0; tc < 8; ++tc){
      size_t idx = (((size_t)tc * 4 + b) * 1024 + n * 128 + i) * 32 + m;
      sr += Pr[idx]; si += Pi[idx];
    }
    xr_s[b][i] = sr * 0.015625f; xi_s[b][i] = si * 0.015625f;
  }
  __syncthreads();
  float accr[4] = {0,0,0,0}, acci[4] = {0,0,0,0};
  size_t wb = (((size_t)n * 32 + m) * 128 + i) * 128;
  for (int j = 0; j < 128; ++j){
    float wr = awr[wb + j], wi = awi[wb + j];
    #pragma unroll
    for (int b = 0; b < 4; ++b){
      accr[b] += wr * xr_s[b][j] - wi * xi_s[b][j];
      acci[b] += wr * xi_s[b][j] + wi * xr_s[b][j];
    }
  }
  #pragma unroll
  for (int b = 0; b < 4; ++b){
    float vr = accr[b], vi = acci[b];
    vr = vr > 0.01f ? vr - 0.01f : (vr < -0.01f ? vr + 0.01f : 0.0f);
    vi = vi > 0.01f ? vi - 0.01f : (vi < -0.01f ? vi + 0.01f : 0.0f);
    size_t dst = ((size_t)b * 32 + m) * 1024 + n * 128 + i;  // [b][m][d]
    Or[dst] = vr; Oi[dst] = vi;
  }
}

// ---------------- kernel D3: d-chunked irfft + residual in-place ----------------
__global__ __launch_bounds__(256) void kernelD3(const float* __restrict__ Or, const float* __restrict__ Oi,
    const float* __restrict__ ctab, const float* __restrict__ stab, float* __restrict__ y){
  __shared__ float cts[32][64], sts[32][64];
  __shared__ float Ors[32][144], Ois[32][144];
  int tid = threadIdx.x;
  int bx = blockIdx.x;
  int b = bx >> 9, tc = (bx >> 3) & 63, dc = bx & 7;
  int t0 = tc * 64, d0 = dc * 128;
  for (int i = 0; i < 8; ++i){
    int lin = i * 256 + tid;
    int m = lin >> 6, tl = lin & 63;
    float f = (m == 0 ? 1.0f : 2.0f) * 0.015625f;
    cts[m][tl] = ctab[m * 4096 + t0 + tl] * f;
    sts[m][tl] = stab[m * 4096 + t0 + tl] * f;
  }
  for (int i = 0; i < 4; ++i){
    int lin = i * 256 + tid;
    int m = lin >> 5, q = lin & 31;
    int w = q * 4;
    int ph = w + ((w >> 5) << 2);
    size_t src = ((size_t)b * 32 + m) * 1024 + d0 + w;
    *(f32x4*)&Ors[m][ph] = *(const f32x4*)&Or[src];
    *(f32x4*)&Ois[m][ph] = *(const f32x4*)&Oi[src];
  }
  __syncthreads();
  int tt = tid >> 4, dl = tid & 15;
  int wb0 = dl * 8;
  int ph0 = wb0 + ((wb0 >> 5) << 2);
  int ph1 = ph0 + 4;
  float acc[4][8];
  #pragma unroll
  for (int q = 0; q < 4; ++q)
    #pragma unroll
    for (int j = 0; j < 8; ++j) acc[q][j] = 0.f;
  for (int m = 0; m < 32; ++m){
    f32x4 cv = *(const f32x4*)&cts[m][tt * 4];
    f32x4 sv = *(const f32x4*)&sts[m][tt * 4];
    f32x4 orv0 = *(const f32x4*)&Ors[m][ph0];
    f32x4 orv1 = *(const f32x4*)&Ors[m][ph1];
    f32x4 oiv0 = *(const f32x4*)&Ois[m][ph0];
    f32x4 oiv1 = *(const f32x4*)&Ois[m][ph1];
    #pragma unroll
    for (int q = 0; q < 4; ++q){
      #pragma unroll
      for (int e = 0; e < 4; ++e){
        acc[q][e]     += cv[q] * orv0[e] - sv[q] * oiv0[e];
        acc[q][4 + e] += cv[q] * orv1[e] - sv[q] * oiv1[e];
      }
    }
  }
  #pragma unroll
  for (int q = 0; q < 4; ++q){
    size_t row = ((size_t)b * 4096 + t0 + tt * 4 + q) * 1024 + d0 + dl * 8;
    f32x4 r0 = *(const f32x4*)&y[row];
    f32x4 r1 = *(const f32x4*)&y[row + 4];
    #pragma unroll
    for (int e = 0; e < 4; ++e){ r0[e] += acc[q][e]; r1[e] += acc[q][4 + e]; }
    *(f32x4*)&y[row] = r0;
    *(f32x4*)&y[row + 4] = r1;
  }
}

// ---------------- LN1: y (f32) -> xln1 (bf16) ----------------
__global__ __launch_bounds__(256) void ln1_k(const float* __restrict__ y,
    const float* __restrict__ g, const float* __restrict__ bb, short* __restrict__ xln){
  size_t row = blockIdx.x;
  int tid = threadIdx.x;
  f32x4 v = *(const f32x4*)(y + row * 1024 + tid * 4);
  float sum = v[0] + v[1] + v[2] + v[3];
  float sq  = v[0]*v[0] + v[1]*v[1] + v[2]*v[2] + v[3]*v[3];
  for (int off = 32; off; off >>= 1){ sum += __shfl_down(sum, off); sq += __shfl_down(sq, off); }
  __shared__ float rs[4], rq[4];
  int lane = tid & 63, w = tid >> 6;
  if (lane == 0){ rs[w] = sum; rq[w] = sq; }
  __syncthreads();
  sum = rs[0] + rs[1] + rs[2] + rs[3]; sq = rq[0] + rq[1] + rq[2] + rq[3];
  float mu = sum * (1.0f / 1024.0f);
  float var = sq * (1.0f / 1024.0f) - mu * mu;
  float sc = rsqrtf(var + 1e-5f);
  s16x4 o;
  #pragma unroll
  for (int j = 0; j < 4; ++j){
    int d = tid * 4 + j;
    o[j] = f2bf((v[j] - mu) * sc * g[d] + bb[d]);
  }
  *(s16x4*)(xln + row * 1024 + tid * 4) = o;
}

// ================= GEMM shared macros (r7, verified) =================
#define LA4(BUF, MIB) { _Pragma("unroll") for (int mi = 0; mi < 4; ++mi){ \
    af[mi][0] = *(const s16x8*)&AsM[(BUF)*16384 + ((MIB)+mi)*2048 + aBase0]; \
    af[mi][1] = *(const s16x8*)&AsM[(BUF)*16384 + ((MIB)+mi)*2048 + aBase1]; } }

// ---------------- GEMM1: 256x256, 8 waves 2Mx4N, K=1024, gelu->bf16 ----------------
__global__ __launch_bounds__(512, 2) void gemm1_k(const short* __restrict__ A,
    const short* __restrict__ BT, const float* __restrict__ bias,
    short* __restrict__ Hout){
  constexpr int K = 1024, NT = 16, N = 4096;
  __shared__ __align__(16) short AsM[2 * 16384];
  __shared__ __align__(16) short BsM[2 * 16384];
  const int tid = threadIdx.x;
  const int lane = tid & 63, wv = tid >> 6;
  const int wr = wv >> 2, wc = wv & 3;
  const int lr = lane & 15, lg = lane >> 4;
  int flat = blockIdx.x;
  int xcd = flat & 7, l = flat >> 3;
  int mb = (xcd & 3) * 8 + (l & 7);
  int nb = (xcd >> 2) * 8 + (l >> 3);
  const int arow0 = mb * 256, bcol0 = nb * 256;

  const int rA = wr * 16 + lr, rB = wc * 16 + lr;
  const int aBase0 = rA * 64 + ((lg       ^ (rA & 7)) * 8);
  const int aBase1 = rA * 64 + (((4 + lg) ^ (rA & 7)) * 8);
  const int bBase0 = rB * 64 + ((lg       ^ (rB & 7)) * 8);
  const int bBase1 = rB * 64 + (((4 + lg) ^ (rB & 7)) * 8);

  const int rr = tid >> 3;
  const int sl8 = ((tid & 7) ^ (rr & 7)) * 8;
  const long aoff = (long)rr * K + sl8;
  const short* Au = A  + (long)arow0 * K;
  const short* Bu = BT + (long)bcol0 * K;
  const int ldsw = wv * 512;

#define SA1(BUF,H,T) { \
  gload16(Au + (long)((H)*128      )*K + (T)*64 + aoff, AsM + (BUF)*16384 + (H)*8192 + ldsw); \
  gload16(Au + (long)((H)*128 + 64 )*K + (T)*64 + aoff, AsM + (BUF)*16384 + (H)*8192 + 4096 + ldsw); }
#define SB1(BUF,H,T) { \
  gload16(Bu + (long)((H)*128      )*K + (T)*64 + aoff, BsM + (BUF)*16384 + (H)*8192 + ldsw); \
  gload16(Bu + (long)((H)*128 + 64 )*K + (T)*64 + aoff, BsM + (BUF)*16384 + (H)*8192 + 4096 + ldsw); }
#define LB2(BUF, DST, NIB) { _Pragma("unroll") for (int ni = 0; ni < 2; ++ni){ \
    DST[ni][0] = *(const s16x8*)&BsM[(BUF)*16384 + ((NIB)+ni)*4096 + bBase0]; \
    DST[ni][1] = *(const s16x8*)&BsM[(BUF)*16384 + ((NIB)+ni)*4096 + bBase1]; } }
#define MQ1(BF, MIB, NIB) { __builtin_amdgcn_s_setprio(1); \
  _Pragma("unroll") for (int ks = 0; ks < 2; ++ks) \
  _Pragma("unroll") for (int mi = 0; mi < 4; ++mi) \
  _Pragma("unroll") for (int ni = 0; ni < 2; ++ni) \
    acc[(MIB)+mi][(NIB)+ni] = __builtin_amdgcn_mfma_f32_16x16x32_bf16( \
        af[mi][ks], BF[ni][ks], acc[(MIB)+mi][(NIB)+ni], 0, 0, 0); \
  __builtin_amdgcn_s_setprio(0); }

  f32x4 acc[8][4] = {};
  s16x8 af[4][2], bfl[2][2], bfh[2][2];

  SA1(0,0,0); SB1(0,1,0); SB1(0,0,0); SA1(0,1,0); SA1(1,0,1); SB1(1,1,1);
  VM(6); SCHED0; BARR; SCHED0;

#define T1(T, BUF) { const bool s1 = (T)+1 < NT, s2 = (T)+2 < NT; \
  LA4(BUF,0); LB2(BUF,bfl,0); \
  if (s1) SB1(1-(BUF),0,(T)+1); \
  SCHED0; BARR; LGKM0; SCHED0; \
  MQ1(bfl,0,0); \
  LB2(BUF,bfh,2); \
  if (s1) SA1(1-(BUF),1,(T)+1); \
  if (s1) { VM(8); } else { VM(0); } \
  SCHED0; BARR; LGKM0; SCHED0; \
  MQ1(bfh,0,2); \
  LA4(BUF,4); \
  if (s2) SA1(BUF,0,(T)+2); \
  SCHED0; BARR; LGKM0; SCHED0; \
  MQ1(bfl,4,0); \
  if (s2) SB1(BUF,1,(T)+2); \
  if (s1) { if (s2) { VM(6); } else { VM(2); } } \
  SCHED0; BARR; SCHED0; \
  MQ1(bfh,4,2); }

  for (int t2 = 0; t2 < NT; t2 += 2){
    T1(t2, 0);
    T1(t2 + 1, 1);
  }
#undef T1
#undef SA1
#undef SB1
#undef LB2
#undef MQ1

  SCHED0;
  const int rb = lg * 4;
  #pragma unroll
  for (int mi = 0; mi < 8; ++mi){
    #pragma unroll
    for (int ni = 0; ni < 4; ++ni){
      int cl = bcol0 + ni * 64 + wc * 16 + lr;
      float bv = bias[cl];
      #pragma unroll
      for (int i = 0; i < 4; ++i){
        long rl = arow0 + mi * 32 + wr * 16 + rb + i;
        float v = acc[mi][ni][i] + bv;
        Hout[rl * (long)N + cl] = f2bf(gelu_f(v));
      }
    }
  }
}

// ---------------- GEMM2: 256x128, 8 waves 2Mx4N (NI=2), K=4096, +bias+resid->f32 ----------------
__global__ __launch_bounds__(512, 2) void gemm2_k(const short* __restrict__ A,
    const short* __restrict__ BT, const float* __restrict__ bias,
    const short* __restrict__ resid, float* __restrict__ Fout, long row0_abs){
  constexpr int K = 4096, NT = 64;
  __shared__ __align__(16) short AsM[2 * 16384];
  __shared__ __align__(16) short BsM[2 * 8192];
  const int tid = threadIdx.x;
  const int lane = tid & 63, wv = tid >> 6;
  const int wr = wv >> 2, wc = wv & 3;
  const int lr = lane & 15, lg = lane >> 4;
  int flat = blockIdx.x;
  int xcd = flat & 7, l = flat >> 3;
  int mb = (xcd & 3) * 8 + (l & 7);
  int nb = (xcd >> 2) * 4 + (l >> 3);
  const int arow0 = mb * 256, bcol0 = nb * 128;

  const int rA = wr * 16 + lr, rB = wc * 16 + lr;
  const int aBase0 = rA * 64 + ((lg       ^ (rA & 7)) * 8);
  const int aBase1 = rA * 64 + (((4 + lg) ^ (rA & 7)) * 8);
  const int bBase0 = rB * 64 + ((lg       ^ (rB & 7)) * 8);
  const int bBase1 = rB * 64 + (((4 + lg) ^ (rB & 7)) * 8);

  const int rr = tid >> 3;
  const int sl8 = ((tid & 7) ^ (rr & 7)) * 8;
  const long aoff = (long)rr * K + sl8;
  const short* Au = A  + (long)arow0 * K;
  const short* Bu = BT + (long)bcol0 * K;
  const int ldsw = wv * 512;

#define SA2(BUF,H,T) { \
  gload16(Au + (long)((H)*128      )*K + (T)*64 + aoff, AsM + (BUF)*16384 + (H)*8192 + ldsw); \
  gload16(Au + (long)((H)*128 + 64 )*K + (T)*64 + aoff, AsM + (BUF)*16384 + (H)*8192 + 4096 + ldsw); }
#define SB2(BUF,H,T) \
  gload16(Bu + (long)((H)*64)*K + (T)*64 + aoff, BsM + (BUF)*8192 + (H)*4096 + ldsw);
#define LB1(BUF, DST, NI) { \
    DST[0] = *(const s16x8*)&BsM[(BUF)*8192 + (NI)*4096 + bBase0]; \
    DST[1] = *(const s16x8*)&BsM[(BUF)*8192 + (NI)*4096 + bBase1]; }
#define MQ2(BF, MIB, NI) { __builtin_amdgcn_s_setprio(1); \
  _Pragma("unroll") for (int ks = 0; ks < 2; ++ks) \
  _Pragma("unroll") for (int mi = 0; mi < 4; ++mi) \
    acc[(MIB)+mi][NI] = __builtin_amdgcn_mfma_f32_16x16x32_bf16( \
        af[mi][ks], BF[ks], acc[(MIB)+mi][NI], 0, 0, 0); \
  __builtin_amdgcn_s_setprio(0); }

  f32x4 acc[8][2] = {};
  s16x8 af[4][2], bfl[2], bfh[2];

  SA2(0,0,0); SB2(0,1,0); SB2(0,0,0); SA2(0,1,0); SA2(1,0,1); SB2(1,1,1);
  VM(5); SCHED0; BARR; SCHED0;

#define T2(T, BUF) { const bool s1 = (T)+1 < NT, s2 = (T)+2 < NT; \
  LA4(BUF,0); LB1(BUF,bfl,0); \
  if (s1) SB2(1-(BUF),0,(T)+1); \
  SCHED0; BARR; LGKM0; SCHED0; \
  MQ2(bfl,0,0); \
  LB1(BUF,bfh,1); \
  if (s1) SA2(1-(BUF),1,(T)+1); \
  if (s1) { VM(6); } else { VM(0); } \
  SCHED0; BARR; LGKM0; SCHED0; \
  MQ2(bfh,0,1); \
  LA4(BUF,4); \
  if (s2) SA2(BUF,0,(T)+2); \
  SCHED0; BARR; LGKM0; SCHED0; \
  MQ2(bfl,4,0); \
  if (s2) SB2(BUF,1,(T)+2); \
  if (s1) { if (s2) { VM(5); } else { VM(2); } } \
  SCHED0; BARR; SCHED0; \
  MQ2(bfh,4,1); }

  for (int t2 = 0; t2 < NT; t2 += 2){
    T2(t2, 0);
    T2(t2 + 1, 1);
  }
#undef T2
#undef SA2
#undef SB2
#undef LB1
#undef MQ2

  SCHED0;
  const int rb = lg * 4;
  #pragma unroll
  for (int mi = 0; mi < 8; ++mi){
    #pragma unroll
    for (int ni = 0; ni < 2; ++ni){
      int cl = bcol0 + ni * 64 + wc * 16 + lr;
      float bv = bias[cl];
      #pragma unroll
      for (int i = 0; i < 4; ++i){
        long rl = arow0 + mi * 32 + wr * 16 + rb + i;
        float v = acc[mi][ni][i] + bv;
        float rv = bf2f(resid[(row0_abs + rl) * 1024 + cl]);
        Fout[(row0_abs + rl) * 1024 + cl] = v + rv;
      }
    }
  }
}

// ---------------- LN2 in-place on f32 out ----------------
__global__ __launch_bounds__(256) void ln2_k(float* __restrict__ out,
    const float* __restrict__ g, const float* __restrict__ bb){
  size_t row = blockIdx.x;
  int tid = threadIdx.x;
  float* p = out + row * 1024;
  f32x4 v = *(const f32x4*)(p + tid * 4);
  float sum = v[0] + v[1] + v[2] + v[3];
  float sq  = v[0]*v[0] + v[1]*v[1] + v[2]*v[2] + v[3]*v[3];
  for (int off = 32; off; off >>= 1){ sum += __shfl_down(sum, off); sq += __shfl_down(sq, off); }
  __shared__ float rs[4], rq[4];
  int lane = tid & 63, w = tid >> 6;
  if (lane == 0){ rs[w] = sum; rq[w] = sq; }
  __syncthreads();
  sum = rs[0] + rs[1] + rs[2] + rs[3]; sq = rq[0] + rq[1] + rq[2] + rq[3];
  float mu = sum * (1.0f / 1024.0f);
  float var = sq * (1.0f / 1024.0f) - mu * mu;
  float sc = rsqrtf(var + 1e-5f);
  f32x4 o;
  #pragma unroll
  for (int j = 0; j < 4; ++j){
    int d = tid * 4 + j;
    o[j] = (v[j] - mu) * sc * g[d] + bb[d];
  }
  *(f32x4*)(p + tid * 4) = o;
}

// ---------------- launch ----------------
extern "C" void kernel_launch(void* const* d_in, const int* in_sizes, int n_in,
                              void* d_out, int out_size, void* d_ws, size_t ws_size,
                              hipStream_t stream){
  (void)in_sizes; (void)n_in; (void)out_size; (void)ws_size;
  const int*   tokens = (const int*)d_in[0];
  const float* frw  = (const float*)d_in[1];
  const float* fiw  = (const float*)d_in[2];
  const float* mw   = (const float*)d_in[3];
  const float* po   = (const float*)d_in[4];
  const float* ftew = (const float*)d_in[5];
  const float* fteb = (const float*)d_in[6];
  const float* posph= (const float*)d_in[7];
  const float* awr  = (const float*)d_in[8];
  const float* awi  = (const float*)d_in[9];
  const float* ln1g = (const float*)d_in[10];
  const float* ln1b = (const float*)d_in[11];
  const float* w1   = (const float*)d_in[12];
  const float* b1   = (const float*)d_in[13];
  const float* w2   = (const float*)d_in[14];
  const float* b2   = (const float*)d_in[15];
  const float* ln2g = (const float*)d_in[16];
  const float* ln2b = (const float*)d_in[17];
  float* out = (float*)d_out;

  char* ws = (char*)d_ws;
  size_t o = 0;
  float* residual = (float*)(ws + o); o += (size_t)16384 * 1024 * 4;  // 67.1 MB; later hbuf
  short* xln1     = (short*)(ws + o); o += (size_t)16384 * 1024 * 2;  // 33.6 MB
  short* w1b      = (short*)(ws + o); o += (size_t)4096 * 1024 * 2;
  short* w2b      = (short*)(ws + o); o += (size_t)4096 * 1024 * 2;
  float* ctab     = (float*)(ws + o); o += 524288;
  float* stab     = (float*)(ws + o); o += 524288;
  float* Or       = (float*)(ws + o); o += 524288;
  float* Oi       = (float*)(ws + o); o += 524288;
  float* Pr       = (float*)(ws + o); o += 4194304;
  float* Pi       = (float*)(ws + o); o += 4194304;
  float* wcs      = (float*)(ws + o); o += 512;
  short* hbuf     = (short*)residual;   // 8192x4096 bf16 aliases dead residual

  prep_tab_k<<<512, 256, 0, stream>>>(ctab, stab, mw, po, wcs);
  transpose_bf16_k<<<dim3(64, 16), 256, 0, stream>>>(w1, w1b, 1024, 4096);
  transpose_bf16_k<<<dim3(16, 64), 256, 0, stream>>>(w2, w2b, 4096, 1024);

  kernelA2<<<1024, 256, 0, stream>>>(tokens, frw, fiw, wcs, ftew, fteb, posph, residual);
  kernelB2<<<1024, 256, 0, stream>>>(residual, Pr, Pi);
  kernelC2<<<256, 128, 0, stream>>>(Pr, Pi, awr, awi, Or, Oi);
  kernelD3<<<2048, 256, 0, stream>>>(Or, Oi, ctab, stab, residual);
  ln1_k<<<16384, 256, 0, stream>>>(residual, ln1g, ln1b, xln1);

  for (int c = 0; c < 2; ++c){
    long row0 = (long)c * 8192;
    gemm1_k<<<512, 512, 0, stream>>>(xln1 + row0 * 1024, w1b, b1, hbuf);
    gemm2_k<<<256, 512, 0, stream>>>(hbuf, w2b, b2, xln1, out, row0);
  }
  ln2_k<<<16384, 256, 0, stream>>>(out, ln2g, ln2b);
}

// Round 11
// 544.126 us; speedup vs baseline: 1.0908x; 1.0356x over previous
//
#include <hip/hip_runtime.h>

// WaveInputEncoder on MI355X — round 11.
// vs r10: kernelA reverted to r7 version (A2 was occupancy/issue-bound, 87.8us).
// GEMMs: unified 256x256 kernel (r7 schedule verbatim), full-M single dispatch
// each (hbuf 134MB, big-path proven by r9), gemm2 widened to BN=256 (grid 256
// = 1 block/CU, no tail). Fusions (prep, reduceB->kernelC) kept.

typedef __attribute__((ext_vector_type(8))) short s16x8;
typedef __attribute__((ext_vector_type(4))) short s16x4;
typedef __attribute__((ext_vector_type(4))) float f32x4;

#define SCHED0 __builtin_amdgcn_sched_barrier(0)
#define BARR   __builtin_amdgcn_s_barrier()
#define LGKM0  asm volatile("s_waitcnt lgkmcnt(0)" ::: "memory")
#define VM(n)  asm volatile("s_waitcnt vmcnt(" #n ")" ::: "memory")

__device__ __forceinline__ short f2bf(float x){
  unsigned u = __float_as_uint(x);
  unsigned r = (u + 0x7fffu + ((u >> 16) & 1u)) >> 16;   // RNE
  return (short)r;
}
__device__ __forceinline__ float bf2f(short x){
  return __uint_as_float(((unsigned)(unsigned short)x) << 16);
}
__device__ __forceinline__ void gload16(const void* g, void* l){
  __builtin_amdgcn_global_load_lds((const __attribute__((address_space(1))) void*)g,
                                   (__attribute__((address_space(3))) void*)l, 16, 0, 0);
}
__device__ __forceinline__ float gelu_f(float v){
  float u2 = v * (0.7978845608f + 0.0356774081f * v * v);
  float e = __expf(2.0f * u2);
  float th = 1.0f - 2.0f / (e + 1.0f);
  return 0.5f * v * (1.0f + th);
}

// ---------------- prep: DFT tables + (block 511) softplus/rot consts ----------------
__global__ __launch_bounds__(256) void prep_tab_k(float* __restrict__ ctab, float* __restrict__ stab,
    const float* __restrict__ mw, const float* __restrict__ po, float* __restrict__ wcs){
  int idx = blockIdx.x * 256 + threadIdx.x;      // idx = m*4096 + t
  int m = idx >> 12, t = idx & 4095;
  int r = (m * t) & 4095;
  float ang = (float)r * 1.5339807878856412e-3f; // 2*pi/4096
  float s, c; sincosf(ang, &s, &c);
  ctab[idx] = c; stab[idx] = s;
  if (blockIdx.x == 511 && threadIdx.x < 32){
    int i = threadIdx.x;
    wcs[i]      = log1pf(expf(mw[i]));
    wcs[32 + i] = cosf(po[i]);
    wcs[64 + i] = sinf(po[i]);
  }
}

// transpose fp32 (R x C) -> bf16 (C x R), 64x64 LDS tiles
__global__ __launch_bounds__(256) void transpose_bf16_k(const float* __restrict__ src,
                                                        short* __restrict__ dst,
                                                        int R, int C){
  __shared__ float tile[64][65];
  int c0 = blockIdx.x * 64, r0 = blockIdx.y * 64;
  for (int i = 0; i < 16; ++i){
    int idx = i * 256 + threadIdx.x;
    int rr = idx >> 6, cc = idx & 63;
    tile[rr][cc] = src[(size_t)(r0 + rr) * C + c0 + cc];
  }
  __syncthreads();
  for (int i = 0; i < 16; ++i){
    int idx = i * 256 + threadIdx.x;
    int cc = idx >> 6, rr = idx & 63;
    dst[(size_t)(c0 + cc) * R + r0 + rr] = f2bf(tile[rr][cc]);
  }
}

// ---------------- kernel A (r7 version): embed + rotate + FTE + positional phase ----------------
__global__ __launch_bounds__(256) void kernelA(const int* __restrict__ tokens,
    const float* __restrict__ frw, const float* __restrict__ fiw,
    const float* __restrict__ wcs, const float* __restrict__ ftew,
    const float* __restrict__ fteb, const float* __restrict__ posph,
    float* __restrict__ xout){
  __shared__ float ffs[4][64];
  __shared__ float xs[4][1024];
  __shared__ float wsh[96];
  int tid = threadIdx.x;
  int b = blockIdx.x >> 10, t0 = (blockIdx.x & 1023) * 4;
  if (tid < 96) wsh[tid] = wcs[tid];
  __syncthreads();
  if (tid < 128){
    int tk = tid >> 5, m = tid & 31;
    int tok = tokens[b * 4096 + t0 + tk];
    float w = wsh[m];
    float re = frw[(size_t)tok * 32 + m] * w;
    float im = fiw[(size_t)tok * 32 + m] * w;
    float c = wsh[32 + m], s = wsh[64 + m];
    ffs[tk][m]      = re * c - im * s;
    ffs[tk][32 + m] = re * s + im * c;
  }
  __syncthreads();
  for (int p = 0; p < 4; ++p){
    int dd = p * 256 + tid;
    float bb = fteb[dd];
    float a0 = bb, a1 = bb, a2 = bb, a3 = bb;
    #pragma unroll 8
    for (int k = 0; k < 64; ++k){
      float wv = ftew[k * 1024 + dd];
      a0 += ffs[0][k] * wv; a1 += ffs[1][k] * wv;
      a2 += ffs[2][k] * wv; a3 += ffs[3][k] * wv;
    }
    xs[0][dd] = a0; xs[1][dd] = a1; xs[2][dd] = a2; xs[3][dd] = a3;
  }
  __syncthreads();
  for (int p = 0; p < 4; ++p){
    int dd = p * 256 + tid, dm = (dd + 1023) & 1023;
    #pragma unroll
    for (int tk = 0; tk < 4; ++tk){
      float pp = posph[(size_t)(t0 + tk) * 1024 + dd];
      float p2 = pp * pp;
      float sp = pp * (1.0f - p2 * (1.0f/6.0f) + p2 * p2 * (1.0f/120.0f));
      float cp = 1.0f - p2 * 0.5f + p2 * p2 * (1.0f/24.0f);
      xout[((size_t)b * 4096 + t0 + tk) * 1024 + dd] = xs[tk][dd] * cp + xs[tk][dm] * sp;
    }
  }
}

// ---------------- kernel B: truncated forward DFT via rotation recurrence ----------------
__global__ __launch_bounds__(256) void kernelB2(const float* __restrict__ xin,
    float* __restrict__ Pr, float* __restrict__ Pi){
  __shared__ float xsh[64][32];
  int tid = threadIdx.x;
  int bx = blockIdx.x;
  int b = bx >> 8, dch = (bx >> 3) & 31, tc = bx & 7;
  int d0 = dch * 32;
  int t_start = tc * 512;
  int dg = tid >> 5, m = tid & 31;
  const float TPN = 1.5339807878856412e-3f;
  int r0 = (m * t_start) & 4095;
  float cw, sw; sincosf(-(float)r0 * TPN, &sw, &cw);
  float cs, ss; sincosf(-(float)m * TPN, &ss, &cs);
  float ar[4] = {0,0,0,0}, ai[4] = {0,0,0,0};
  for (int t0 = t_start; t0 < t_start + 512; t0 += 64){
    __syncthreads();
    #pragma unroll
    for (int i = 0; i < 2; ++i){
      int unit = i * 256 + tid;
      int tt = unit >> 3, du = (unit & 7) * 4;
      *(f32x4*)&xsh[tt][du] = *(const f32x4*)&xin[((size_t)b * 4096 + t0 + tt) * 1024 + d0 + du];
    }
    __syncthreads();
    #pragma unroll 4
    for (int tt = 0; tt < 64; ++tt){
      f32x4 xv = *(const f32x4*)&xsh[tt][dg * 4];
      #pragma unroll
      for (int j = 0; j < 4; ++j){ ar[j] += xv[j] * cw; ai[j] += xv[j] * sw; }
      float cn = cw * cs - sw * ss;
      sw = cw * ss + sw * cs; cw = cn;
    }
  }
  #pragma unroll
  for (int j = 0; j < 4; ++j){
    int d = d0 + dg * 4 + j;
    size_t idx = (((size_t)tc * 4 + b) * 1024 + d) * 32 + m;
    Pr[idx] = ar[j]; Pi[idx] = ai[j];
  }
}

// ---------------- kernel C (with fused tc-reduction of Pr/Pi) ----------------
__global__ __launch_bounds__(128) void kernelC2(const float* __restrict__ Pr, const float* __restrict__ Pi,
    const float* __restrict__ awr, const float* __restrict__ awi,
    float* __restrict__ Or, float* __restrict__ Oi){
  __shared__ float xr_s[4][128], xi_s[4][128];
  int nm = blockIdx.x; int n = nm >> 5, m = nm & 31;
  int i = threadIdx.x;
  #pragma unroll
  for (int b = 0; b < 4; ++b){
    float sr = 0.0f, si = 0.0f;
    #pragma unroll
    for (int tc = 0; tc < 8; ++tc){
      size_t idx = (((size_t)tc * 4 + b) * 1024 + n * 128 + i) * 32 + m;
      sr += Pr[idx]; si += Pi[idx];
    }
    xr_s[b][i] = sr * 0.015625f; xi_s[b][i] = si * 0.015625f;
  }
  __syncthreads();
  float accr[4] = {0,0,0,0}, acci[4] = {0,0,0,0};
  size_t wb = (((size_t)n * 32 + m) * 128 + i) * 128;
  for (int j = 0; j < 128; ++j){
    float wr = awr[wb + j], wi = awi[wb + j];
    #pragma unroll
    for (int b = 0; b < 4; ++b){
      accr[b] += wr * xr_s[b][j] - wi * xi_s[b][j];
      acci[b] += wr * xi_s[b][j] + wi * xr_s[b][j];
    }
  }
  #pragma unroll
  for (int b = 0; b < 4; ++b){
    float vr = accr[b], vi = acci[b];
    vr = vr > 0.01f ? vr - 0.01f : (vr < -0.01f ? vr + 0.01f : 0.0f);
    vi = vi > 0.01f ? vi - 0.01f : (vi < -0.01f ? vi + 0.01f : 0.0f);
    size_t dst = ((size_t)b * 32 + m) * 1024 + n * 128 + i;  // [b][m][d]
    Or[dst] = vr; Oi[dst] = vi;
  }
}

// ---------------- kernel D3: d-chunked irfft + residual in-place ----------------
__global__ __launch_bounds__(256) void kernelD3(const float* __restrict__ Or, const float* __restrict__ Oi,
    const float* __restrict__ ctab, const float* __restrict__ stab, float* __restrict__ y){
  __shared__ float cts[32][64], sts[32][64];
  __shared__ float Ors[32][144], Ois[32][144];
  int tid = threadIdx.x;
  int bx = blockIdx.x;
  int b = bx >> 9, tc = (bx >> 3) & 63, dc = bx & 7;
  int t0 = tc * 64, d0 = dc * 128;
  for (int i = 0; i < 8; ++i){
    int lin = i * 256 + tid;
    int m = lin >> 6, tl = lin & 63;
    float f = (m == 0 ? 1.0f : 2.0f) * 0.015625f;
    cts[m][tl] = ctab[m * 4096 + t0 + tl] * f;
    sts[m][tl] = stab[m * 4096 + t0 + tl] * f;
  }
  for (int i = 0; i < 4; ++i){
    int lin = i * 256 + tid;
    int m = lin >> 5, q = lin & 31;
    int w = q * 4;
    int ph = w + ((w >> 5) << 2);
    size_t src = ((size_t)b * 32 + m) * 1024 + d0 + w;
    *(f32x4*)&Ors[m][ph] = *(const f32x4*)&Or[src];
    *(f32x4*)&Ois[m][ph] = *(const f32x4*)&Oi[src];
  }
  __syncthreads();
  int tt = tid >> 4, dl = tid & 15;
  int wb0 = dl * 8;
  int ph0 = wb0 + ((wb0 >> 5) << 2);
  int ph1 = ph0 + 4;
  float acc[4][8];
  #pragma unroll
  for (int q = 0; q < 4; ++q)
    #pragma unroll
    for (int j = 0; j < 8; ++j) acc[q][j] = 0.f;
  for (int m = 0; m < 32; ++m){
    f32x4 cv = *(const f32x4*)&cts[m][tt * 4];
    f32x4 sv = *(const f32x4*)&sts[m][tt * 4];
    f32x4 orv0 = *(const f32x4*)&Ors[m][ph0];
    f32x4 orv1 = *(const f32x4*)&Ors[m][ph1];
    f32x4 oiv0 = *(const f32x4*)&Ois[m][ph0];
    f32x4 oiv1 = *(const f32x4*)&Ois[m][ph1];
    #pragma unroll
    for (int q = 0; q < 4; ++q){
      #pragma unroll
      for (int e = 0; e < 4; ++e){
        acc[q][e]     += cv[q] * orv0[e] - sv[q] * oiv0[e];
        acc[q][4 + e] += cv[q] * orv1[e] - sv[q] * oiv1[e];
      }
    }
  }
  #pragma unroll
  for (int q = 0; q < 4; ++q){
    size_t row = ((size_t)b * 4096 + t0 + tt * 4 + q) * 1024 + d0 + dl * 8;
    f32x4 r0 = *(const f32x4*)&y[row];
    f32x4 r1 = *(const f32x4*)&y[row + 4];
    #pragma unroll
    for (int e = 0; e < 4; ++e){ r0[e] += acc[q][e]; r1[e] += acc[q][4 + e]; }
    *(f32x4*)&y[row] = r0;
    *(f32x4*)&y[row + 4] = r1;
  }
}

// ---------------- LN1: y (f32) -> xln1 (bf16) ----------------
__global__ __launch_bounds__(256) void ln1_k(const float* __restrict__ y,
    const float* __restrict__ g, const float* __restrict__ bb, short* __restrict__ xln){
  size_t row = blockIdx.x;
  int tid = threadIdx.x;
  f32x4 v = *(const f32x4*)(y + row * 1024 + tid * 4);
  float sum = v[0] + v[1] + v[2] + v[3];
  float sq  = v[0]*v[0] + v[1]*v[1] + v[2]*v[2] + v[3]*v[3];
  for (int off = 32; off; off >>= 1){ sum += __shfl_down(sum, off); sq += __shfl_down(sq, off); }
  __shared__ float rs[4], rq[4];
  int lane = tid & 63, w = tid >> 6;
  if (lane == 0){ rs[w] = sum; rq[w] = sq; }
  __syncthreads();
  sum = rs[0] + rs[1] + rs[2] + rs[3]; sq = rq[0] + rq[1] + rq[2] + rq[3];
  float mu = sum * (1.0f / 1024.0f);
  float var = sq * (1.0f / 1024.0f) - mu * mu;
  float sc = rsqrtf(var + 1e-5f);
  s16x4 o;
  #pragma unroll
  for (int j = 0; j < 4; ++j){
    int d = tid * 4 + j;
    o[j] = f2bf((v[j] - mu) * sc * g[d] + bb[d]);
  }
  *(s16x4*)(xln + row * 1024 + tid * 4) = o;
}

// ================= unified 256x256 GEMM (r7 schedule) =================
// 8 waves 2Mx4N, BK=64, 4-phase/K-tile, counted vmcnt, 0-conflict swizzle.
// EPI 0: gelu -> bf16 Hout (stride N). EPI 1: +bias+resid -> f32 Fout (stride 1024).
// Block mapping: per-XCD compact tiles; mq = (Mrows/256)/4 rows-blocks per
// XCD-quadrant, nqh = (grid/8)/mq col-blocks per XCD-half.
#define LA4(BUF, MIB) { _Pragma("unroll") for (int mi = 0; mi < 4; ++mi){ \
    af[mi][0] = *(const s16x8*)&AsM[(BUF)*16384 + ((MIB)+mi)*2048 + aBase0]; \
    af[mi][1] = *(const s16x8*)&AsM[(BUF)*16384 + ((MIB)+mi)*2048 + aBase1]; } }

template<int EPI>
__global__ __launch_bounds__(512, 2) void gemm_k(const short* __restrict__ A,
    const short* __restrict__ BT, const float* __restrict__ bias,
    const short* __restrict__ resid, short* __restrict__ Hout,
    float* __restrict__ Fout, int K, int N, int Mrows, long row0_abs){
  const int NT = K >> 6;
  __shared__ __align__(16) short AsM[2 * 16384];
  __shared__ __align__(16) short BsM[2 * 16384];
  const int tid = threadIdx.x;
  const int lane = tid & 63, wv = tid >> 6;
  const int wr = wv >> 2, wc = wv & 3;
  const int lr = lane & 15, lg = lane >> 4;

  int flat = blockIdx.x;
  int xcd = flat & 7, l = flat >> 3;
  int mq = Mrows >> 10;                       // (M/256)/4
  int nqh = (int)(gridDim.x >> 3) / mq;
  int mb = (xcd & 3) * mq + (l % mq);
  int nb = (xcd >> 2) * nqh + (l / mq);
  const int arow0 = mb * 256, bcol0 = nb * 256;

  const int rA = wr * 16 + lr, rB = wc * 16 + lr;
  const int aBase0 = rA * 64 + ((lg       ^ (rA & 7)) * 8);
  const int aBase1 = rA * 64 + (((4 + lg) ^ (rA & 7)) * 8);
  const int bBase0 = rB * 64 + ((lg       ^ (rB & 7)) * 8);
  const int bBase1 = rB * 64 + (((4 + lg) ^ (rB & 7)) * 8);

  const int rr = tid >> 3;
  const int sl8 = ((tid & 7) ^ (rr & 7)) * 8;
  const long aoff = (long)rr * K + sl8;
  const short* Au = A  + (long)arow0 * K;
  const short* Bu = BT + (long)bcol0 * K;
  const int ldsw = wv * 512;

#define SA1(BUF,H,T) { \
  gload16(Au + (long)((H)*128      )*K + (T)*64 + aoff, AsM + (BUF)*16384 + (H)*8192 + ldsw); \
  gload16(Au + (long)((H)*128 + 64 )*K + (T)*64 + aoff, AsM + (BUF)*16384 + (H)*8192 + 4096 + ldsw); }
#define SB1(BUF,H,T) { \
  gload16(Bu + (long)((H)*128      )*K + (T)*64 + aoff, BsM + (BUF)*16384 + (H)*8192 + ldsw); \
  gload16(Bu + (long)((H)*128 + 64 )*K + (T)*64 + aoff, BsM + (BUF)*16384 + (H)*8192 + 4096 + ldsw); }
#define LB2(BUF, DST, NIB) { _Pragma("unroll") for (int ni = 0; ni < 2; ++ni){ \
    DST[ni][0] = *(const s16x8*)&BsM[(BUF)*16384 + ((NIB)+ni)*4096 + bBase0]; \
    DST[ni][1] = *(const s16x8*)&BsM[(BUF)*16384 + ((NIB)+ni)*4096 + bBase1]; } }
#define MQ1(BF, MIB, NIB) { __builtin_amdgcn_s_setprio(1); \
  _Pragma("unroll") for (int ks = 0; ks < 2; ++ks) \
  _Pragma("unroll") for (int mi = 0; mi < 4; ++mi) \
  _Pragma("unroll") for (int ni = 0; ni < 2; ++ni) \
    acc[(MIB)+mi][(NIB)+ni] = __builtin_amdgcn_mfma_f32_16x16x32_bf16( \
        af[mi][ks], BF[ni][ks], acc[(MIB)+mi][(NIB)+ni], 0, 0, 0); \
  __builtin_amdgcn_s_setprio(0); }

  f32x4 acc[8][4] = {};
  s16x8 af[4][2], bfl[2][2], bfh[2][2];

  SA1(0,0,0); SB1(0,1,0); SB1(0,0,0); SA1(0,1,0); SA1(1,0,1); SB1(1,1,1);
  VM(6); SCHED0; BARR; SCHED0;

#define T1(T, BUF) { const bool s1 = (T)+1 < NT, s2 = (T)+2 < NT; \
  LA4(BUF,0); LB2(BUF,bfl,0); \
  if (s1) SB1(1-(BUF),0,(T)+1); \
  SCHED0; BARR; LGKM0; SCHED0; \
  MQ1(bfl,0,0); \
  LB2(BUF,bfh,2); \
  if (s1) SA1(1-(BUF),1,(T)+1); \
  if (s1) { VM(8); } else { VM(0); } \
  SCHED0; BARR; LGKM0; SCHED0; \
  MQ1(bfh,0,2); \
  LA4(BUF,4); \
  if (s2) SA1(BUF,0,(T)+2); \
  SCHED0; BARR; LGKM0; SCHED0; \
  MQ1(bfl,4,0); \
  if (s2) SB1(BUF,1,(T)+2); \
  if (s1) { if (s2) { VM(6); } else { VM(2); } } \
  SCHED0; BARR; SCHED0; \
  MQ1(bfh,4,2); }

  for (int t2 = 0; t2 < NT; t2 += 2){
    T1(t2, 0);
    T1(t2 + 1, 1);
  }
#undef T1
#undef SA1
#undef SB1
#undef LB2
#undef MQ1

  SCHED0;
  const int rb = lg * 4;
  #pragma unroll
  for (int mi = 0; mi < 8; ++mi){
    #pragma unroll
    for (int ni = 0; ni < 4; ++ni){
      int cl = bcol0 + ni * 64 + wc * 16 + lr;
      float bv = bias[cl];
      #pragma unroll
      for (int i = 0; i < 4; ++i){
        long rl = arow0 + mi * 32 + wr * 16 + rb + i;
        float v = acc[mi][ni][i] + bv;
        if constexpr (EPI == 0){
          Hout[rl * (long)N + cl] = f2bf(gelu_f(v));
        } else {
          float rv = bf2f(resid[(row0_abs + rl) * 1024 + cl]);
          Fout[(row0_abs + rl) * 1024 + cl] = v + rv;
        }
      }
    }
  }
}

// ---------------- LN2 in-place on f32 out ----------------
__global__ __launch_bounds__(256) void ln2_k(float* __restrict__ out,
    const float* __restrict__ g, const float* __restrict__ bb){
  size_t row = blockIdx.x;
  int tid = threadIdx.x;
  float* p = out + row * 1024;
  f32x4 v = *(const f32x4*)(p + tid * 4);
  float sum = v[0] + v[1] + v[2] + v[3];
  float sq  = v[0]*v[0] + v[1]*v[1] + v[2]*v[2] + v[3]*v[3];
  for (int off = 32; off; off >>= 1){ sum += __shfl_down(sum, off); sq += __shfl_down(sq, off); }
  __shared__ float rs[4], rq[4];
  int lane = tid & 63, w = tid >> 6;
  if (lane == 0){ rs[w] = sum; rq[w] = sq; }
  __syncthreads();
  sum = rs[0] + rs[1] + rs[2] + rs[3]; sq = rq[0] + rq[1] + rq[2] + rq[3];
  float mu = sum * (1.0f / 1024.0f);
  float var = sq * (1.0f / 1024.0f) - mu * mu;
  float sc = rsqrtf(var + 1e-5f);
  f32x4 o;
  #pragma unroll
  for (int j = 0; j < 4; ++j){
    int d = tid * 4 + j;
    o[j] = (v[j] - mu) * sc * g[d] + bb[d];
  }
  *(f32x4*)(p + tid * 4) = o;
}

// ---------------- launch ----------------
extern "C" void kernel_launch(void* const* d_in, const int* in_sizes, int n_in,
                              void* d_out, int out_size, void* d_ws, size_t ws_size,
                              hipStream_t stream){
  (void)in_sizes; (void)n_in; (void)out_size;
  const int*   tokens = (const int*)d_in[0];
  const float* frw  = (const float*)d_in[1];
  const float* fiw  = (const float*)d_in[2];
  const float* mw   = (const float*)d_in[3];
  const float* po   = (const float*)d_in[4];
  const float* ftew = (const float*)d_in[5];
  const float* fteb = (const float*)d_in[6];
  const float* posph= (const float*)d_in[7];
  const float* awr  = (const float*)d_in[8];
  const float* awi  = (const float*)d_in[9];
  const float* ln1g = (const float*)d_in[10];
  const float* ln1b = (const float*)d_in[11];
  const float* w1   = (const float*)d_in[12];
  const float* b1   = (const float*)d_in[13];
  const float* w2   = (const float*)d_in[14];
  const float* b2   = (const float*)d_in[15];
  const float* ln2g = (const float*)d_in[16];
  const float* ln2b = (const float*)d_in[17];
  float* out = (float*)d_out;

  const size_t HB_BIG   = (size_t)16384 * 4096 * 2;   // 134.2 MB full-M hbuf
  const size_t HB_SMALL = (size_t)16384 * 1024 * 4;   // 67.1 MB (residual-sized)
  const size_t TAIL = (size_t)16384 * 1024 * 2        // xln1
                    + 2 * (size_t)4096 * 1024 * 2     // w1b, w2b
                    + 4 * 524288                      // ctab, stab, Or, Oi
                    + 2 * 4194304                     // Pr, Pi
                    + 512;                            // wcs
  const bool big = ws_size >= HB_BIG + TAIL;
  const size_t hb = big ? HB_BIG : HB_SMALL;

  char* ws = (char*)d_ws;
  size_t o = 0;
  float* residual = (float*)(ws + o); o += hb;        // head doubles as hbuf
  short* hbuf     = (short*)residual;
  short* xln1     = (short*)(ws + o); o += (size_t)16384 * 1024 * 2;
  short* w1b      = (short*)(ws + o); o += (size_t)4096 * 1024 * 2;
  short* w2b      = (short*)(ws + o); o += (size_t)4096 * 1024 * 2;
  float* ctab     = (float*)(ws + o); o += 524288;
  float* stab     = (float*)(ws + o); o += 524288;
  float* Or       = (float*)(ws + o); o += 524288;
  float* Oi       = (float*)(ws + o); o += 524288;
  float* Pr       = (float*)(ws + o); o += 4194304;
  float* Pi      = (float*)(ws + o); o += 4194304;
  float* wcs      = (float*)(ws + o); o += 512;

  prep_tab_k<<<512, 256, 0, stream>>>(ctab, stab, mw, po, wcs);
  transpose_bf16_k<<<dim3(64, 16), 256, 0, stream>>>(w1, w1b, 1024, 4096);
  transpose_bf16_k<<<dim3(16, 64), 256, 0, stream>>>(w2, w2b, 4096, 1024);

  kernelA<<<4096, 256, 0, stream>>>(tokens, frw, fiw, wcs, ftew, fteb, posph, residual);
  kernelB2<<<1024, 256, 0, stream>>>(residual, Pr, Pi);
  kernelC2<<<256, 128, 0, stream>>>(Pr, Pi, awr, awi, Or, Oi);
  kernelD3<<<2048, 256, 0, stream>>>(Or, Oi, ctab, stab, residual);
  ln1_k<<<16384, 256, 0, stream>>>(residual, ln1g, ln1b, xln1);

  if (big){
    gemm_k<0><<<1024, 512, 0, stream>>>(xln1, w1b, b1, nullptr, hbuf, nullptr,
                                        1024, 4096, 16384, 0);
    gemm_k<1><<<256, 512, 0, stream>>>(hbuf, w2b, b2, xln1, nullptr, out,
                                       4096, 1024, 16384, 0);
  } else {
    for (int c = 0; c < 2; ++c){
      long row0 = (long)c * 8192;
      gemm_k<0><<<512, 512, 0, stream>>>(xln1 + row0 * 1024, w1b, b1, nullptr,
                                         hbuf, nullptr, 1024, 4096, 8192, 0);
      gemm_k<1><<<128, 512, 0, stream>>>(hbuf, w2b, b2, xln1, nullptr, out,
                                         4096, 1024, 8192, row0);
    }
  }
  ln2_k<<<16384, 256, 0, stream>>>(out, ln2g, ln2b);
}